// Round 11
// baseline (119.078 us; speedup 1.0000x reference)
//
#include <hip/hip_runtime.h>

#define N_FFT 4096
#define NH    2048          // N_FFT/2 (complex FFT length)
#define NBINS 2049          // N_FFT/2 + 1
#define NLAGS 81            // 2*MAX_TAU + 1
#define MAXTAU 40
#define NSEG  8             // k-segments per (b,p) pair
#define SEGLEN 256
#define PI_F 3.14159265358979323846f
#define PAD(i) ((i) + ((i) >> 4))   // LDS bank-conflict padding (+1 per 16)

// e^{-2*pi*i/4096} as f32 constants (cos, sin)
#define CQ 0.99999882345f
#define SQ 0.00153398019f

// ---------------------------------------------------------------------------
// Kernel 1: rfft per (b,m) channel, fp32, packed-complex radix-2 FFT in LDS.
// Postprocess twiddle e^{-2pi i k/4096} via parity trick on the stage table
// (even k: tw[k/2]; odd k: tw[k/2] * e^{-2pi i/4096}; k=2048: (-1,0)) --
// removes ~4100 sincosf per block. Also zeroes cc/key/ticket for downstream
// atomics.
// ---------------------------------------------------------------------------
__global__ __launch_bounds__(1024)
void rfft_kernel(const float* __restrict__ sig,
                 float* __restrict__ S,
                 float* __restrict__ cc, int ccN,
                 unsigned long long* __restrict__ key,
                 int* __restrict__ ticket, int B) {
    int bm  = (int)blockIdx.x;
    int tid = (int)threadIdx.x;

    __shared__ float2 data[PAD(NH - 1) + 1];   // 2175 float2 = 17.0 KB
    __shared__ float2 tw[NH / 2];              //  8 KB

    // zero cc/key/ticket for the atomic accumulation downstream
    for (int i = bm * 1024 + tid; i < ccN; i += (int)gridDim.x * 1024)
        cc[i] = 0.0f;
    if (bm == 0 && tid < B) { key[tid] = 0ull; ticket[tid] = 0; }

    // twiddle table: one entry per thread
    {
        float sv, cv;
        sincosf(-(2.0f * PI_F / (float)NH) * (float)tid, &sv, &cv);
        tw[tid] = make_float2(cv, sv);
    }

    // load packed real pairs, scatter to bit-reversed position
    const float2* sp = (const float2*)(sig + (size_t)bm * N_FFT);
    for (int i = tid; i < NH; i += 1024) {
        float2 v = sp[i];
        int j = (int)(__brev((unsigned)i) >> 21);   // 11-bit reverse
        data[PAD(j)] = v;
    }
    __syncthreads();

    // 11 radix-2 DIT stages, 1024 butterflies each (1 per thread)
    for (int s = 1; s <= 11; ++s) {
        int half = 1 << (s - 1);
        int g  = tid >> (s - 1);
        int j  = tid & (half - 1);
        int i0 = (g << s) + j;
        int i1 = i0 + half;
        float2 w = tw[j << (11 - s)];
        float2 u = data[PAD(i0)];
        float2 v = data[PAD(i1)];
        float vr = v.x * w.x - v.y * w.y;
        float vi = v.x * w.y + v.y * w.x;
        data[PAD(i0)] = make_float2(u.x + vr, u.y + vi);
        data[PAD(i1)] = make_float2(u.x - vr, u.y - vi);
        __syncthreads();
    }

    // real-split postprocess -> X[0..2048], parity-trick twiddle
    float* So = S + (size_t)bm * NBINS * 2;
    for (int k = tid; k < NBINS; k += 1024) {
        float2 Zk = data[PAD(k & (NH - 1))];
        float2 Zm = data[PAD((NH - k) & (NH - 1))];
        float er = 0.5f * (Zk.x + Zm.x);
        float ei = 0.5f * (Zk.y - Zm.y);
        float dr = Zk.x - Zm.x;
        float di = Zk.y + Zm.y;
        float orr = 0.5f * di;       // O = -i*d/2
        float oii = -0.5f * dr;
        float2 W;
        if (k == 2048) {
            W = make_float2(-1.0f, 0.0f);
        } else {
            float2 t = tw[k >> 1];
            if (k & 1) W = make_float2(t.x * CQ + t.y * SQ,
                                       t.y * CQ - t.x * SQ);
            else       W = t;
        }
        So[k * 2]     = er + W.x * orr - W.y * oii;
        So[k * 2 + 1] = ei + W.x * oii + W.y * orr;
    }
}

// ---------------------------------------------------------------------------
// Kernel 2: per (b,p,seg): PHAT (irfft weight folded) for 256(+1) bins into
// LDS, then lag partials via n/-n symmetry; fp32 atomicAdd into cc.
// (No __threadfence anywhere — per-block device fences are the R5/R9 killer.)
// ---------------------------------------------------------------------------
#define NCH 6
#define CHLEN 43
__global__ __launch_bounds__(256)
void phat_cc_kernel(const float* __restrict__ S,
                    const int* __restrict__ comb,
                    float* __restrict__ cc, int P) {
    int id  = (int)blockIdx.x;
    int seg = id & (NSEG - 1);
    int bp  = id >> 3;
    int b   = bp / P;
    int p   = bp % P;
    int ma = comb[p * 2 + 0];
    int mb = comb[p * 2 + 1];
    const float2* Sa = (const float2*)(S + ((size_t)(b * 8 + ma)) * NBINS * 2);
    const float2* Sb = (const float2*)(S + ((size_t)(b * 8 + mb)) * NBINS * 2);

    int k0 = seg * SEGLEN;
    int k1 = (seg == NSEG - 1) ? NBINS : (k0 + SEGLEN);   // last seg: 257 bins

    __shared__ float2 phs[SEGLEN + 1];       // 2,056 B
    __shared__ float partCr[41 * NCH];       //   984 B
    __shared__ float partCi[41 * NCH];

    int tid = (int)threadIdx.x;
    for (int k = k0 + tid; k < k1; k += 256) {
        float2 a = Sa[k];
        float2 c = Sb[k];
        float Xr = a.x * c.x + a.y * c.y;     // Sa * conj(Sb)
        float Xi = a.y * c.x - a.x * c.y;
        float mag = sqrtf(Xr * Xr + Xi * Xi);
        float w = (k == 0 || k == 2048) ? 1.0f : 2.0f;
        float inv = w / (mag + 1e-12f);
        phs[k - k0] = make_float2(Xr * inv, Xi * inv);
    }
    __syncthreads();

    if (tid < 41 * NCH) {
        int n = tid % 41;                      // |lag| 0..40
        int c = tid / 41;
        int kk0 = k0 + c * CHLEN;
        int kk1 = kk0 + CHLEN;
        if (kk1 > k1) kk1 = k1;

        float step = (2.0f * PI_F / (float)N_FFT) * (float)n;
        float sv, cv;
        sincosf(step, &sv, &cv);
        float wr = cv, wi = sv;               // e^{+i step}
        sincosf(step * (float)kk0, &sv, &cv);
        float rr = cv, ri = sv;               // e^{+i step kk0}

        float Cr = 0.0f, Ci = 0.0f;
        for (int k = kk0; k < kk1; ++k) {
            float2 ph = phs[k - k0];
            Cr = fmaf(ph.x, rr, Cr);
            Ci = fmaf(ph.y, ri, Ci);
            float nr = rr * wr - ri * wi;
            float ni = rr * wi + ri * wr;
            rr = nr; ri = ni;
        }
        partCr[tid] = Cr;
        partCi[tid] = Ci;
    }
    __syncthreads();

    if (tid < 41) {
        float Cr = 0.0f, Ci = 0.0f;
        #pragma unroll
        for (int c = 0; c < NCH; ++c) {
            Cr += partCr[tid + 41 * c];
            Ci += partCi[tid + 41 * c];
        }
        float* outp = cc + (size_t)bp * NLAGS;
        atomicAdd(&outp[MAXTAU + tid], Cr - Ci);
        if (tid > 0) atomicAdd(&outp[MAXTAU - tid], Cr + Ci);
    }
}

// ---------------------------------------------------------------------------
// Kernel 3: grid = (chunk, batch). cc[b] staged in LDS (x 1/N); per-thread
// power; block argmax; one packed u64 atomicMax per block:
//   ((monotone-f32)<<32) | (~gi)  == np.argmax first-max tie-break exactly.
// Then s_waitcnt(0) (pure pipeline drain, NO cache writeback) before the
// ticket atomicAdd -> atomicMax is complete at the coherence point before
// the ticket increments. Last block per batch decodes key[b] -> out[b].
// ---------------------------------------------------------------------------
__global__ __launch_bounds__(256)
void power_argmax_kernel(const float* __restrict__ cc,
                         const int* __restrict__ tau,
                         int G, int P, int nchunks,
                         unsigned long long* __restrict__ key,
                         int* __restrict__ ticket,
                         const float* __restrict__ grid_x,
                         const float* __restrict__ rec_centroid,
                         float* __restrict__ out) {
    int b     = (int)blockIdx.y;
    int chunk = (int)blockIdx.x;
    int tid   = (int)threadIdx.x;

    __shared__ float ccs[28 * NLAGS];   // 9,072 B
    const float* csrc = cc + (size_t)b * P * NLAGS;
    for (int i = tid; i < 28 * NLAGS; i += 256)
        ccs[i] = csrc[i] * (1.0f / (float)N_FFT);
    __syncthreads();

    int g = chunk * 256 + tid;
    float v = -1e30f;
    int   gi = 0x7fffffff;
    if (g < G) {
        const int4* tp = (const int4*)(tau + (size_t)g * 28);
        v = 0.0f;
        #pragma unroll
        for (int q = 0; q < 7; ++q) {
            int4 tv = tp[q];
            v += ccs[(q * 4 + 0) * NLAGS + tv.x];
            v += ccs[(q * 4 + 1) * NLAGS + tv.y];
            v += ccs[(q * 4 + 2) * NLAGS + tv.z];
            v += ccs[(q * 4 + 3) * NLAGS + tv.w];
        }
        v += 0.0f;   // canonicalize -0 -> +0
        gi = g;
    }

    #pragma unroll
    for (int off = 32; off > 0; off >>= 1) {
        float v2 = __shfl_down(v, off);
        int   i2 = __shfl_down(gi, off);
        if (v2 > v || (v2 == v && i2 < gi)) { v = v2; gi = i2; }
    }
    __shared__ float wval[4];
    __shared__ int   widx[4];
    int lane = tid & 63, wv = tid >> 6;
    if (lane == 0) { wval[wv] = v; widx[wv] = gi; }
    __syncthreads();
    if (tid == 0) {
        #pragma unroll
        for (int w = 1; w < 4; ++w) {
            float v2 = wval[w]; int i2 = widx[w];
            if (v2 > v || (v2 == v && i2 < gi)) { v = v2; gi = i2; }
        }
        unsigned fb = __float_as_uint(v);
        unsigned u  = (fb & 0x80000000u) ? ~fb : (fb | 0x80000000u);
        unsigned long long k =
            ((unsigned long long)u << 32) |
            (unsigned long long)(0xffffffffu - (unsigned)gi);
        atomicMax(&key[b], k);
        __builtin_amdgcn_s_waitcnt(0);   // drain vmem: atomicMax done at L2
        int old = atomicAdd(&ticket[b], 1);
        if (old == nchunks - 1) {
            unsigned long long kk = atomicOr(&key[b], 0ull);   // coherent read
            unsigned fgi = 0xffffffffu - (unsigned)(kk & 0xffffffffu);
            for (int c = 0; c < 3; ++c)
                out[b * 3 + c] = grid_x[(size_t)fgi * 3 + c] - rec_centroid[c];
        }
    }
}

extern "C" void kernel_launch(void* const* d_in, const int* in_sizes, int n_in,
                              void* d_out, int out_size, void* d_ws, size_t ws_size,
                              hipStream_t stream) {
    const float* signal       = (const float*)d_in[0];
    const float* grid_x       = (const float*)d_in[1];
    const int*   tau          = (const int*)d_in[2];
    const int*   comb         = (const int*)d_in[3];
    const float* rec_centroid = (const float*)d_in[4];
    float* out = (float*)d_out;

    int G  = in_sizes[1] / 3;          // ~31416 grid points
    int P  = in_sizes[3] / 2;          // 28 pairs
    int BM = in_sizes[0] / N_FFT;      // 128 channels
    int B  = BM / 8;                   // 16 batches
    int BP = B * P;                    // 448

    // workspace layout
    float* S  = (float*)d_ws;                      // BM*2049*2 floats (2.1 MB)
    float* cc = S + (size_t)BM * NBINS * 2;        // BP*81 floats
    unsigned long long* key = (unsigned long long*)(cc + (size_t)BP * NLAGS); // B (8B-aligned)
    int* ticket = (int*)(key + B);                 // B ints
    int nchunks = (G + 255) / 256;

    rfft_kernel<<<BM, 1024, 0, stream>>>(signal, S, cc, BP * NLAGS, key, ticket, B);
    phat_cc_kernel<<<BP * NSEG, 256, 0, stream>>>(S, comb, cc, P);
    power_argmax_kernel<<<dim3(nchunks, B), 256, 0, stream>>>(
        cc, tau, G, P, nchunks, key, ticket, grid_x, rec_centroid, out);
}

// Round 12
// 96.615 us; speedup vs baseline: 1.2325x; 1.2325x over previous
//
#include <hip/hip_runtime.h>

#define N_FFT 4096
#define NH    2048          // N_FFT/2 (complex FFT length)
#define NBINS 2049          // N_FFT/2 + 1
#define NLAGS 81            // 2*MAX_TAU + 1
#define MAXTAU 40
#define NSEG  8             // k-segments per (b,p) pair
#define SEGLEN 256
#define PI_F 3.14159265358979323846f
#define PAD(i) ((i) + ((i) >> 4))   // LDS bank-conflict padding (+1 per 16)

// e^{-2*pi*i/4096} as f32 constants (cos, sin)
#define CQ 0.99999882345f
#define SQ 0.00153398019f

__device__ __forceinline__ float2 cmul(float2 a, float2 b) {
    return make_float2(a.x * b.x - a.y * b.y, a.x * b.y + a.y * b.x);
}

// ---------------------------------------------------------------------------
// Kernel 1: rfft per (b,m) channel, fp32, packed-complex FFT in LDS.
// Two radix-2 stages per barrier (radix-4 dataflow, no digit reversal):
// each thread reads 4 elements, applies stages (s,s+1) in registers, writes 4.
// LDS stage traffic halves, barriers 11 -> 6. 512 threads, 1 group/thread.
// Postprocess twiddles via parity trick (no sincosf). Zeroes cc for phat.
// ---------------------------------------------------------------------------
__global__ __launch_bounds__(512)
void rfft_kernel(const float* __restrict__ sig,
                 float* __restrict__ S,
                 float* __restrict__ cc, int ccN) {
    int bm  = (int)blockIdx.x;
    int tid = (int)threadIdx.x;

    __shared__ float2 data[PAD(NH - 1) + 1];   // 2175 float2 = 17.4 KB
    __shared__ float2 tw[NH / 2];              //  8 KB

    // zero cc for the atomic accumulation downstream
    for (int i = bm * 512 + tid; i < ccN; i += (int)gridDim.x * 512)
        cc[i] = 0.0f;

    // twiddle table
    for (int j = tid; j < NH / 2; j += 512) {
        float sv, cv;
        sincosf(-(2.0f * PI_F / (float)NH) * (float)j, &sv, &cv);
        tw[j] = make_float2(cv, sv);
    }

    // load packed real pairs, scatter to bit-reversed position
    const float2* sp = (const float2*)(sig + (size_t)bm * N_FFT);
    for (int i = tid; i < NH; i += 512) {
        float2 v = sp[i];
        int j = (int)(__brev((unsigned)i) >> 21);   // 11-bit reverse
        data[PAD(j)] = v;
    }
    __syncthreads();

    // stages 1..10 as 5 combined passes (two radix-2 levels per barrier)
    for (int s = 1; s <= 9; s += 2) {
        int h  = 1 << (s - 1);
        int j  = tid & (h - 1);
        int g  = tid >> (s - 1);
        int i0 = (g << (s + 1)) + j;
        int i1 = i0 + h, i2 = i0 + 2 * h, i3 = i0 + 3 * h;

        float2 w1 = tw[j << (11 - s)];
        float2 wA = tw[j << (10 - s)];
        float2 wB = tw[(j + h) << (10 - s)];

        float2 a = data[PAD(i0)];
        float2 b = data[PAD(i1)];
        float2 c = data[PAD(i2)];
        float2 d = data[PAD(i3)];

        // stage s
        float2 wb = cmul(w1, b), wd = cmul(w1, d);
        float2 a1 = make_float2(a.x + wb.x, a.y + wb.y);
        float2 b1 = make_float2(a.x - wb.x, a.y - wb.y);
        float2 c1 = make_float2(c.x + wd.x, c.y + wd.y);
        float2 d1 = make_float2(c.x - wd.x, c.y - wd.y);
        // stage s+1
        float2 wc = cmul(wA, c1), wdd = cmul(wB, d1);
        data[PAD(i0)] = make_float2(a1.x + wc.x,  a1.y + wc.y);
        data[PAD(i2)] = make_float2(a1.x - wc.x,  a1.y - wc.y);
        data[PAD(i1)] = make_float2(b1.x + wdd.x, b1.y + wdd.y);
        data[PAD(i3)] = make_float2(b1.x - wdd.x, b1.y - wdd.y);
        __syncthreads();
    }

    // stage 11 (half = 1024): 1024 butterflies, 2 per thread
    for (int t = tid; t < 1024; t += 512) {
        int i0 = t, i1 = t + 1024;
        float2 w = tw[t];
        float2 u = data[PAD(i0)];
        float2 v = data[PAD(i1)];
        float2 wv = cmul(w, v);
        data[PAD(i0)] = make_float2(u.x + wv.x, u.y + wv.y);
        data[PAD(i1)] = make_float2(u.x - wv.x, u.y - wv.y);
    }
    __syncthreads();

    // real-split postprocess -> X[0..2048], parity-trick twiddle
    float* So = S + (size_t)bm * NBINS * 2;
    for (int k = tid; k < NBINS; k += 512) {
        float2 Zk = data[PAD(k & (NH - 1))];
        float2 Zm = data[PAD((NH - k) & (NH - 1))];
        float er = 0.5f * (Zk.x + Zm.x);
        float ei = 0.5f * (Zk.y - Zm.y);
        float dr = Zk.x - Zm.x;
        float di = Zk.y + Zm.y;
        float orr = 0.5f * di;       // O = -i*d/2
        float oii = -0.5f * dr;
        float2 W;
        if (k == 2048) {
            W = make_float2(-1.0f, 0.0f);
        } else {
            float2 t = tw[k >> 1];
            if (k & 1) W = make_float2(t.x * CQ + t.y * SQ,
                                       t.y * CQ - t.x * SQ);
            else       W = t;
        }
        So[k * 2]     = er + W.x * orr - W.y * oii;
        So[k * 2 + 1] = ei + W.x * oii + W.y * orr;
    }
}

// ---------------------------------------------------------------------------
// Kernel 2: per (b,p,seg): PHAT (irfft weight folded) for 256(+1) bins into
// LDS, then lag partials via n/-n symmetry; fp32 atomicAdd into cc.
// (No fences, no cross-block protocols — R5/R9/R11 lesson.)
// ---------------------------------------------------------------------------
#define NCH 6
#define CHLEN 43
__global__ __launch_bounds__(256)
void phat_cc_kernel(const float* __restrict__ S,
                    const int* __restrict__ comb,
                    float* __restrict__ cc, int P) {
    int id  = (int)blockIdx.x;
    int seg = id & (NSEG - 1);
    int bp  = id >> 3;
    int b   = bp / P;
    int p   = bp % P;
    int ma = comb[p * 2 + 0];
    int mb = comb[p * 2 + 1];
    const float2* Sa = (const float2*)(S + ((size_t)(b * 8 + ma)) * NBINS * 2);
    const float2* Sb = (const float2*)(S + ((size_t)(b * 8 + mb)) * NBINS * 2);

    int k0 = seg * SEGLEN;
    int k1 = (seg == NSEG - 1) ? NBINS : (k0 + SEGLEN);   // last seg: 257 bins

    __shared__ float2 phs[SEGLEN + 1];       // 2,056 B
    __shared__ float partCr[41 * NCH];       //   984 B
    __shared__ float partCi[41 * NCH];

    int tid = (int)threadIdx.x;
    for (int k = k0 + tid; k < k1; k += 256) {
        float2 a = Sa[k];
        float2 c = Sb[k];
        float Xr = a.x * c.x + a.y * c.y;     // Sa * conj(Sb)
        float Xi = a.y * c.x - a.x * c.y;
        float mag = sqrtf(Xr * Xr + Xi * Xi);
        float w = (k == 0 || k == 2048) ? 1.0f : 2.0f;
        float inv = w / (mag + 1e-12f);
        phs[k - k0] = make_float2(Xr * inv, Xi * inv);
    }
    __syncthreads();

    if (tid < 41 * NCH) {
        int n = tid % 41;                      // |lag| 0..40
        int c = tid / 41;
        int kk0 = k0 + c * CHLEN;
        int kk1 = kk0 + CHLEN;
        if (kk1 > k1) kk1 = k1;

        float step = (2.0f * PI_F / (float)N_FFT) * (float)n;
        float sv, cv;
        sincosf(step, &sv, &cv);
        float wr = cv, wi = sv;               // e^{+i step}
        sincosf(step * (float)kk0, &sv, &cv);
        float rr = cv, ri = sv;               // e^{+i step kk0}

        float Cr = 0.0f, Ci = 0.0f;
        for (int k = kk0; k < kk1; ++k) {
            float2 ph = phs[k - k0];
            Cr = fmaf(ph.x, rr, Cr);
            Ci = fmaf(ph.y, ri, Ci);
            float nr = rr * wr - ri * wi;
            float ni = rr * wi + ri * wr;
            rr = nr; ri = ni;
        }
        partCr[tid] = Cr;
        partCi[tid] = Ci;
    }
    __syncthreads();

    if (tid < 41) {
        float Cr = 0.0f, Ci = 0.0f;
        #pragma unroll
        for (int c = 0; c < NCH; ++c) {
            Cr += partCr[tid + 41 * c];
            Ci += partCi[tid + 41 * c];
        }
        float* outp = cc + (size_t)bp * NLAGS;
        atomicAdd(&outp[MAXTAU + tid], Cr - Ci);
        if (tid > 0) atomicAdd(&outp[MAXTAU - tid], Cr + Ci);
    }
}

// ---------------------------------------------------------------------------
// Kernel 3: grid = (chunk, batch). cc[b] staged in LDS (x 1/N); per-thread
// power; wave-shuffle argmax (ties -> lowest index, matching np.argmax).
// Plain stores of block results (NO fence, NO last-block fusion).
// ---------------------------------------------------------------------------
__global__ __launch_bounds__(256)
void power_argmax_kernel(const float* __restrict__ cc,
                         const int* __restrict__ tau,
                         int G, int P,
                         float* __restrict__ pval,
                         int* __restrict__ pidx, int nchunks) {
    int b     = (int)blockIdx.y;
    int chunk = (int)blockIdx.x;
    int tid   = (int)threadIdx.x;

    __shared__ float ccs[28 * NLAGS];   // 9,072 B
    const float* csrc = cc + (size_t)b * P * NLAGS;
    for (int i = tid; i < 28 * NLAGS; i += 256)
        ccs[i] = csrc[i] * (1.0f / (float)N_FFT);
    __syncthreads();

    int g = chunk * 256 + tid;
    float v = -1e30f;
    int   gi = 0x7fffffff;
    if (g < G) {
        const int4* tp = (const int4*)(tau + (size_t)g * 28);
        v = 0.0f;
        #pragma unroll
        for (int q = 0; q < 7; ++q) {
            int4 tv = tp[q];
            v += ccs[(q * 4 + 0) * NLAGS + tv.x];
            v += ccs[(q * 4 + 1) * NLAGS + tv.y];
            v += ccs[(q * 4 + 2) * NLAGS + tv.z];
            v += ccs[(q * 4 + 3) * NLAGS + tv.w];
        }
        gi = g;
    }

    #pragma unroll
    for (int off = 32; off > 0; off >>= 1) {
        float v2 = __shfl_down(v, off);
        int   i2 = __shfl_down(gi, off);
        if (v2 > v || (v2 == v && i2 < gi)) { v = v2; gi = i2; }
    }
    __shared__ float wval[4];
    __shared__ int   widx[4];
    int lane = tid & 63, wv = tid >> 6;
    if (lane == 0) { wval[wv] = v; widx[wv] = gi; }
    __syncthreads();
    if (tid == 0) {
        #pragma unroll
        for (int w = 1; w < 4; ++w) {
            float v2 = wval[w]; int i2 = widx[w];
            if (v2 > v || (v2 == v && i2 < gi)) { v = v2; gi = i2; }
        }
        pval[b * nchunks + chunk] = v;
        pidx[b * nchunks + chunk] = gi;
    }
}

// ---------------------------------------------------------------------------
// Kernel 4: final reduction over chunks (one block per batch, one wave).
// ---------------------------------------------------------------------------
__global__ void finalize_kernel(const float* __restrict__ pval,
                                const int* __restrict__ pidx, int nchunks,
                                const float* __restrict__ grid_x,
                                const float* __restrict__ rec_centroid,
                                float* __restrict__ out) {
    int b = (int)blockIdx.x;
    int l = (int)threadIdx.x;
    float v = -1e30f; int gi = 0x7fffffff;
    for (int j = l; j < nchunks; j += 64) {
        float v2 = pval[b * nchunks + j];
        int   i2 = pidx[b * nchunks + j];
        if (v2 > v || (v2 == v && i2 < gi)) { v = v2; gi = i2; }
    }
    #pragma unroll
    for (int off = 32; off > 0; off >>= 1) {
        float v2 = __shfl_down(v, off);
        int   i2 = __shfl_down(gi, off);
        if (v2 > v || (v2 == v && i2 < gi)) { v = v2; gi = i2; }
    }
    if (l == 0) {
        for (int c = 0; c < 3; ++c)
            out[b * 3 + c] = grid_x[(size_t)gi * 3 + c] - rec_centroid[c];
    }
}

extern "C" void kernel_launch(void* const* d_in, const int* in_sizes, int n_in,
                              void* d_out, int out_size, void* d_ws, size_t ws_size,
                              hipStream_t stream) {
    const float* signal       = (const float*)d_in[0];
    const float* grid_x       = (const float*)d_in[1];
    const int*   tau          = (const int*)d_in[2];
    const int*   comb         = (const int*)d_in[3];
    const float* rec_centroid = (const float*)d_in[4];
    float* out = (float*)d_out;

    int G  = in_sizes[1] / 3;          // ~31416 grid points
    int P  = in_sizes[3] / 2;          // 28 pairs
    int BM = in_sizes[0] / N_FFT;      // 128 channels
    int B  = BM / 8;                   // 16 batches
    int BP = B * P;                    // 448

    // workspace layout (4B-aligned throughout)
    float* S  = (float*)d_ws;                      // BM*2049*2 floats (2.1 MB)
    float* cc = S + (size_t)BM * NBINS * 2;        // BP*81 floats
    int nchunks = (G + 255) / 256;
    float* pval = cc + (size_t)BP * NLAGS;
    int*   pidx = (int*)(pval + (size_t)B * nchunks);

    rfft_kernel<<<BM, 512, 0, stream>>>(signal, S, cc, BP * NLAGS);
    phat_cc_kernel<<<BP * NSEG, 256, 0, stream>>>(S, comb, cc, P);
    power_argmax_kernel<<<dim3(nchunks, B), 256, 0, stream>>>(cc, tau, G, P, pval, pidx, nchunks);
    finalize_kernel<<<B, 64, 0, stream>>>(pval, pidx, nchunks, grid_x, rec_centroid, out);
}

// Round 13
// 93.631 us; speedup vs baseline: 1.2718x; 1.0319x over previous
//
#include <hip/hip_runtime.h>

#define N_FFT 4096
#define NH    2048          // N_FFT/2 (complex FFT length)
#define NBINS 2049          // N_FFT/2 + 1
#define NLAGS 81            // 2*MAX_TAU + 1
#define MAXTAU 40
#define NSEG  8             // k-segments per (b,p) pair
#define SEGLEN 256
#define PI_F 3.14159265358979323846f
#define PAD(i) ((i) + ((i) >> 4))   // LDS bank-conflict padding (+1 per 16)

// e^{-2*pi*i/4096} as f32 constants (cos, sin)
#define CQ 0.99999882345f
#define SQ 0.00153398019f

__device__ __forceinline__ float2 cmul(float2 a, float2 b) {
    return make_float2(a.x * b.x - a.y * b.y, a.x * b.y + a.y * b.x);
}

// ---------------------------------------------------------------------------
// Kernel 1: rfft per (b,m) channel, fp32, packed-complex FFT in LDS.
// Two radix-2 stages per barrier (radix-4 dataflow). Postprocess twiddles via
// parity trick; S written as vectorized float2. Zeroes cc for phat atomics.
// ---------------------------------------------------------------------------
__global__ __launch_bounds__(512)
void rfft_kernel(const float* __restrict__ sig,
                 float* __restrict__ S,
                 float* __restrict__ cc, int ccN) {
    int bm  = (int)blockIdx.x;
    int tid = (int)threadIdx.x;

    __shared__ float2 data[PAD(NH - 1) + 1];   // 2175 float2 = 17.4 KB
    __shared__ float2 tw[NH / 2];              //  8 KB

    // zero cc for the atomic accumulation downstream
    for (int i = bm * 512 + tid; i < ccN; i += (int)gridDim.x * 512)
        cc[i] = 0.0f;

    // twiddle table
    for (int j = tid; j < NH / 2; j += 512) {
        float sv, cv;
        sincosf(-(2.0f * PI_F / (float)NH) * (float)j, &sv, &cv);
        tw[j] = make_float2(cv, sv);
    }

    // load packed real pairs, scatter to bit-reversed position
    const float2* sp = (const float2*)(sig + (size_t)bm * N_FFT);
    for (int i = tid; i < NH; i += 512) {
        float2 v = sp[i];
        int j = (int)(__brev((unsigned)i) >> 21);   // 11-bit reverse
        data[PAD(j)] = v;
    }
    __syncthreads();

    // stages 1..10 as 5 combined passes (two radix-2 levels per barrier)
    for (int s = 1; s <= 9; s += 2) {
        int h  = 1 << (s - 1);
        int j  = tid & (h - 1);
        int g  = tid >> (s - 1);
        int i0 = (g << (s + 1)) + j;
        int i1 = i0 + h, i2 = i0 + 2 * h, i3 = i0 + 3 * h;

        float2 w1 = tw[j << (11 - s)];
        float2 wA = tw[j << (10 - s)];
        float2 wB = tw[(j + h) << (10 - s)];

        float2 a = data[PAD(i0)];
        float2 b = data[PAD(i1)];
        float2 c = data[PAD(i2)];
        float2 d = data[PAD(i3)];

        // stage s
        float2 wb = cmul(w1, b), wd = cmul(w1, d);
        float2 a1 = make_float2(a.x + wb.x, a.y + wb.y);
        float2 b1 = make_float2(a.x - wb.x, a.y - wb.y);
        float2 c1 = make_float2(c.x + wd.x, c.y + wd.y);
        float2 d1 = make_float2(c.x - wd.x, c.y - wd.y);
        // stage s+1
        float2 wc = cmul(wA, c1), wdd = cmul(wB, d1);
        data[PAD(i0)] = make_float2(a1.x + wc.x,  a1.y + wc.y);
        data[PAD(i2)] = make_float2(a1.x - wc.x,  a1.y - wc.y);
        data[PAD(i1)] = make_float2(b1.x + wdd.x, b1.y + wdd.y);
        data[PAD(i3)] = make_float2(b1.x - wdd.x, b1.y - wdd.y);
        __syncthreads();
    }

    // stage 11 (half = 1024): 1024 butterflies, 2 per thread
    for (int t = tid; t < 1024; t += 512) {
        int i0 = t, i1 = t + 1024;
        float2 w = tw[t];
        float2 u = data[PAD(i0)];
        float2 v = data[PAD(i1)];
        float2 wv = cmul(w, v);
        data[PAD(i0)] = make_float2(u.x + wv.x, u.y + wv.y);
        data[PAD(i1)] = make_float2(u.x - wv.x, u.y - wv.y);
    }
    __syncthreads();

    // real-split postprocess -> X[0..2048], parity-trick twiddle, float2 store
    float2* So = (float2*)(S + (size_t)bm * NBINS * 2);
    for (int k = tid; k < NBINS; k += 512) {
        float2 Zk = data[PAD(k & (NH - 1))];
        float2 Zm = data[PAD((NH - k) & (NH - 1))];
        float er = 0.5f * (Zk.x + Zm.x);
        float ei = 0.5f * (Zk.y - Zm.y);
        float dr = Zk.x - Zm.x;
        float di = Zk.y + Zm.y;
        float orr = 0.5f * di;       // O = -i*d/2
        float oii = -0.5f * dr;
        float2 W;
        if (k == 2048) {
            W = make_float2(-1.0f, 0.0f);
        } else {
            float2 t = tw[k >> 1];
            if (k & 1) W = make_float2(t.x * CQ + t.y * SQ,
                                       t.y * CQ - t.x * SQ);
            else       W = t;
        }
        So[k] = make_float2(er + W.x * orr - W.y * oii,
                            ei + W.x * oii + W.y * orr);
    }
}

// ---------------------------------------------------------------------------
// Kernel 2: per (b,p,seg): PHAT (irfft weight folded) for 256(+1) bins into
// LDS, then lag partials via n/-n symmetry; fp32 atomicAdd into cc.
// (No fences, no cross-block protocols — R5/R9/R11 lesson.)
// ---------------------------------------------------------------------------
#define NCH 6
#define CHLEN 43
__global__ __launch_bounds__(256)
void phat_cc_kernel(const float* __restrict__ S,
                    const int* __restrict__ comb,
                    float* __restrict__ cc, int P) {
    int id  = (int)blockIdx.x;
    int seg = id & (NSEG - 1);
    int bp  = id >> 3;
    int b   = bp / P;
    int p   = bp % P;
    int ma = comb[p * 2 + 0];
    int mb = comb[p * 2 + 1];
    const float2* Sa = (const float2*)(S + ((size_t)(b * 8 + ma)) * NBINS * 2);
    const float2* Sb = (const float2*)(S + ((size_t)(b * 8 + mb)) * NBINS * 2);

    int k0 = seg * SEGLEN;
    int k1 = (seg == NSEG - 1) ? NBINS : (k0 + SEGLEN);   // last seg: 257 bins

    __shared__ float2 phs[SEGLEN + 1];       // 2,056 B
    __shared__ float partCr[41 * NCH];       //   984 B
    __shared__ float partCi[41 * NCH];

    int tid = (int)threadIdx.x;
    for (int k = k0 + tid; k < k1; k += 256) {
        float2 a = Sa[k];
        float2 c = Sb[k];
        float Xr = a.x * c.x + a.y * c.y;     // Sa * conj(Sb)
        float Xi = a.y * c.x - a.x * c.y;
        float mag = sqrtf(Xr * Xr + Xi * Xi);
        float w = (k == 0 || k == 2048) ? 1.0f : 2.0f;
        float inv = w / (mag + 1e-12f);
        phs[k - k0] = make_float2(Xr * inv, Xi * inv);
    }
    __syncthreads();

    if (tid < 41 * NCH) {
        int n = tid % 41;                      // |lag| 0..40
        int c = tid / 41;
        int kk0 = k0 + c * CHLEN;
        int kk1 = kk0 + CHLEN;
        if (kk1 > k1) kk1 = k1;

        float step = (2.0f * PI_F / (float)N_FFT) * (float)n;
        float sv, cv;
        sincosf(step, &sv, &cv);
        float wr = cv, wi = sv;               // e^{+i step}
        sincosf(step * (float)kk0, &sv, &cv);
        float rr = cv, ri = sv;               // e^{+i step kk0}

        float Cr = 0.0f, Ci = 0.0f;
        for (int k = kk0; k < kk1; ++k) {
            float2 ph = phs[k - k0];
            Cr = fmaf(ph.x, rr, Cr);
            Ci = fmaf(ph.y, ri, Ci);
            float nr = rr * wr - ri * wi;
            float ni = rr * wi + ri * wr;
            rr = nr; ri = ni;
        }
        partCr[tid] = Cr;
        partCi[tid] = Ci;
    }
    __syncthreads();

    if (tid < 41) {
        float Cr = 0.0f, Ci = 0.0f;
        #pragma unroll
        for (int c = 0; c < NCH; ++c) {
            Cr += partCr[tid + 41 * c];
            Ci += partCi[tid + 41 * c];
        }
        float* outp = cc + (size_t)bp * NLAGS;
        atomicAdd(&outp[MAXTAU + tid], Cr - Ci);
        if (tid > 0) atomicAdd(&outp[MAXTAU - tid], Cr + Ci);
    }
}

// ---------------------------------------------------------------------------
// Kernel 3: grid = (chunk, batch), 512 threads (512 grid points per block:
// halves cc-staging traffic vs 256). cc[b] staged via float4; per-thread
// power; wave-shuffle argmax (ties -> lowest index, matching np.argmax).
// Plain stores of block results (NO fence, NO last-block fusion).
// ---------------------------------------------------------------------------
__global__ __launch_bounds__(512)
void power_argmax_kernel(const float* __restrict__ cc,
                         const int* __restrict__ tau,
                         int G, int P,
                         float* __restrict__ pval,
                         int* __restrict__ pidx, int nchunks) {
    int b     = (int)blockIdx.y;
    int chunk = (int)blockIdx.x;
    int tid   = (int)threadIdx.x;

    __shared__ float ccs[28 * NLAGS];   // 9,072 B (2268 floats = 567 float4)
    const float4* csrc = (const float4*)(cc + (size_t)b * P * NLAGS);
    float4* cdst = (float4*)ccs;
    const float scale = 1.0f / (float)N_FFT;
    for (int i = tid; i < 28 * NLAGS / 4; i += 512) {
        float4 v = csrc[i];
        cdst[i] = make_float4(v.x * scale, v.y * scale, v.z * scale, v.w * scale);
    }
    __syncthreads();

    int g = chunk * 512 + tid;
    float v = -1e30f;
    int   gi = 0x7fffffff;
    if (g < G) {
        const int4* tp = (const int4*)(tau + (size_t)g * 28);
        v = 0.0f;
        #pragma unroll
        for (int q = 0; q < 7; ++q) {
            int4 tv = tp[q];
            v += ccs[(q * 4 + 0) * NLAGS + tv.x];
            v += ccs[(q * 4 + 1) * NLAGS + tv.y];
            v += ccs[(q * 4 + 2) * NLAGS + tv.z];
            v += ccs[(q * 4 + 3) * NLAGS + tv.w];
        }
        gi = g;
    }

    #pragma unroll
    for (int off = 32; off > 0; off >>= 1) {
        float v2 = __shfl_down(v, off);
        int   i2 = __shfl_down(gi, off);
        if (v2 > v || (v2 == v && i2 < gi)) { v = v2; gi = i2; }
    }
    __shared__ float wval[8];
    __shared__ int   widx[8];
    int lane = tid & 63, wv = tid >> 6;
    if (lane == 0) { wval[wv] = v; widx[wv] = gi; }
    __syncthreads();
    if (tid == 0) {
        #pragma unroll
        for (int w = 1; w < 8; ++w) {
            float v2 = wval[w]; int i2 = widx[w];
            if (v2 > v || (v2 == v && i2 < gi)) { v = v2; gi = i2; }
        }
        pval[b * nchunks + chunk] = v;
        pidx[b * nchunks + chunk] = gi;
    }
}

// ---------------------------------------------------------------------------
// Kernel 4: final reduction over chunks (one block per batch, one wave).
// ---------------------------------------------------------------------------
__global__ void finalize_kernel(const float* __restrict__ pval,
                                const int* __restrict__ pidx, int nchunks,
                                const float* __restrict__ grid_x,
                                const float* __restrict__ rec_centroid,
                                float* __restrict__ out) {
    int b = (int)blockIdx.x;
    int l = (int)threadIdx.x;
    float v = -1e30f; int gi = 0x7fffffff;
    for (int j = l; j < nchunks; j += 64) {
        float v2 = pval[b * nchunks + j];
        int   i2 = pidx[b * nchunks + j];
        if (v2 > v || (v2 == v && i2 < gi)) { v = v2; gi = i2; }
    }
    #pragma unroll
    for (int off = 32; off > 0; off >>= 1) {
        float v2 = __shfl_down(v, off);
        int   i2 = __shfl_down(gi, off);
        if (v2 > v || (v2 == v && i2 < gi)) { v = v2; gi = i2; }
    }
    if (l == 0) {
        for (int c = 0; c < 3; ++c)
            out[b * 3 + c] = grid_x[(size_t)gi * 3 + c] - rec_centroid[c];
    }
}

extern "C" void kernel_launch(void* const* d_in, const int* in_sizes, int n_in,
                              void* d_out, int out_size, void* d_ws, size_t ws_size,
                              hipStream_t stream) {
    const float* signal       = (const float*)d_in[0];
    const float* grid_x       = (const float*)d_in[1];
    const int*   tau          = (const int*)d_in[2];
    const int*   comb         = (const int*)d_in[3];
    const float* rec_centroid = (const float*)d_in[4];
    float* out = (float*)d_out;

    int G  = in_sizes[1] / 3;          // ~31416 grid points
    int P  = in_sizes[3] / 2;          // 28 pairs
    int BM = in_sizes[0] / N_FFT;      // 128 channels
    int B  = BM / 8;                   // 16 batches
    int BP = B * P;                    // 448

    // workspace layout (16B-aligned throughout: offsets are multiples of 16)
    float* S  = (float*)d_ws;                      // BM*2049*2 floats (2.1 MB)
    float* cc = S + (size_t)BM * NBINS * 2;        // BP*81 floats
    int nchunks = (G + 511) / 512;
    float* pval = cc + (size_t)BP * NLAGS;
    int*   pidx = (int*)(pval + (size_t)B * nchunks);

    rfft_kernel<<<BM, 512, 0, stream>>>(signal, S, cc, BP * NLAGS);
    phat_cc_kernel<<<BP * NSEG, 256, 0, stream>>>(S, comb, cc, P);
    power_argmax_kernel<<<dim3(nchunks, B), 512, 0, stream>>>(cc, tau, G, P, pval, pidx, nchunks);
    finalize_kernel<<<B, 64, 0, stream>>>(pval, pidx, nchunks, grid_x, rec_centroid, out);
}